// Round 7
// baseline (40194.791 us; speedup 1.0000x reference)
//
#include <hip/hip_runtime.h>

// 2-layer tanh RNN, B=64, S=2048, D=HID=512.
// Round 14: hierarchical rendezvous — 8-wave blocks, block stamps, LDS-
// coalesced h stores. Same tiling as r13 (16 cols x K=1024 per wave,
// register-resident weights), same PROVEN transport (DEPTH=64 rotation,
// plain write-through stores + vmcnt ack, plain coalesced loads, TCC-RMW
// stamp reads). r13 post-mortem: fast adopted (WRITE 282MB) and bit-correct
// but 11.5us/step: convoy over 32 independent producer waves (per-step max
// of 32 jittery latencies) + 256 scattered 2B stores on the pre-stamp
// drain + 64 stamp lines x 64 pollers.
// New packaging:
//   block = 512 thr = 8 waves = (group g, layer L, quarter qb):
//     16 rows x 128 cols; grid 64, active blockIdx%8 = g in 0..3 =>
//     all 16 blocks of a group on ONE XCD (r10/r11-proven mapping).
//   - intra-block 8-wave min absorbed by __syncthreads (its implicit
//     vmcnt(0) doubles as the store drain); ONE stamp per block.
//   - h store: C/D frags -> 4KB LDS tile -> 64 x 8B contiguous stores.
//   - cross-block wait: 4 quarter-stamps per layer (8 lines/group);
//     lanes 0-7 poll via TCC-RMW, ballot-MIN, s_sleep backoff.
// Waits: L0@t: all4(L0)>=t && all4(L1)>=t-63 (WAR). L1@t: all4(L0)>=t+1
// && all4(L1)>=t. Within-layer WAR implied (<=1-step skew in-layer).
// Probe (24 steps, slow-truth mirror+compare) validates the new protocol
// bit-exact; verdict!=0 => slow path + 2ms telemetry stall (~18ms PASS).

#define SEQ    2048
#define PROBE  24
#define DEPTH  64
#define DMASK  (DEPTH - 1)
#define FSTR   32              // ints between stamps = 128 B

typedef _Float16 half8 __attribute__((ext_vector_type(8)));
typedef float floatx4 __attribute__((ext_vector_type(4)));
typedef unsigned long long u64;

__device__ inline half8 cvt8(const float* p) {
    float4 f0 = ((const float4*)p)[0];
    float4 f1 = ((const float4*)p)[1];
    half8 h;
    h[0]=(_Float16)f0.x; h[1]=(_Float16)f0.y; h[2]=(_Float16)f0.z; h[3]=(_Float16)f0.w;
    h[4]=(_Float16)f1.x; h[5]=(_Float16)f1.y; h[6]=(_Float16)f1.z; h[7]=(_Float16)f1.w;
    return h;
}

// ===== agent-scope (MALL) primitives — round-7 proven slow/truth path =====
__device__ inline u64 ld8_l3(const void* p) {
    return __hip_atomic_load((const u64*)p, __ATOMIC_RELAXED, __HIP_MEMORY_SCOPE_AGENT);
}
__device__ inline half8 ldfrag_l3(const _Float16* p) {
    union { u64 d[2]; half8 h; } u;
    u.d[0] = ld8_l3(p); u.d[1] = ld8_l3(p + 4);
    return u.h;
}
__device__ inline int ldflag_l3(const int* p) {
    return __hip_atomic_load(p, __ATOMIC_RELAXED, __HIP_MEMORY_SCOPE_AGENT);
}
__device__ inline void st2_l3(_Float16* p, unsigned short v) {
    __hip_atomic_store((unsigned short*)p, v, __ATOMIC_RELAXED, __HIP_MEMORY_SCOPE_AGENT);
}
__device__ inline void stflag_l3(int* p, int v) {
    __hip_atomic_store(p, v, __ATOMIC_RELAXED, __HIP_MEMORY_SCOPE_AGENT);
}

// ===== XCD-local fast primitives (r10/r11/r13-proven) =====
__device__ inline int ldstamp(int* p) {              // TCC-RMW, L1-bypassing
    return __hip_atomic_fetch_add(p, 0, __ATOMIC_RELAXED,
                                  __HIP_MEMORY_SCOPE_WORKGROUP);
}
__device__ inline void ststamp(int* p, int v) {
    __hip_atomic_store(p, v, __ATOMIC_RELAXED, __HIP_MEMORY_SCOPE_WORKGROUP);
}
__device__ inline half8 ldfrag_fast(const _Float16* p) {
    return *reinterpret_cast<const half8*>(p);       // global_load_dwordx4
}

__device__ inline int neq8(half8 a, half8 b) {
    union { half8 h; u64 d[2]; } ua, ub; ua.h = a; ub.h = b;
    return (ua.d[0] != ub.d[0]) | (ua.d[1] != ub.d[1]);
}

#define MFMA(a, b, c) __builtin_amdgcn_mfma_f32_16x16x32_f16((a), (b), (c), 0, 0, 0)

// ===== slow path (agent scope, 4 slots, per-wave packed stamps) — proven =====
__device__ __forceinline__ void run_slow(
    const int t0, const int lane, const int L, const int bg, const int jg,
    const int* __restrict__ src, const float* __restrict__ embed,
    const half8* bw, const float bias, float* __restrict__ out,
    _Float16* h0s, _Float16* h1s, int* flg)
{
    const int q    = lane >> 4;
    const int rr   = lane & 15;
    const int col  = jg * 16 + rr;
    const int arow = bg * 16 + rr;
    const int lf   = lane >> 5;

    for (int t = t0; t < SEQ; ++t) {
        floatx4 acc0 = {0.f,0.f,0.f,0.f}, acc1 = {0.f,0.f,0.f,0.f};

        if (L == 0) {
            const int erow = src[arow * SEQ + t];
            const float* eb = embed + (size_t)erow * 512 + q * 8;
            half8 ax[16];
            #pragma unroll
            for (int u = 0; u < 16; ++u) ax[u] = cvt8(eb + u * 32);
            #pragma unroll
            for (int u = 0; u < 16; ++u) {
                if (u & 1) acc1 = MFMA(ax[u], bw[u], acc1);
                else       acc0 = MFMA(ax[u], bw[u], acc0);
            }
            const int tgt = (lf == 0) ? t : (t - 3);
            for (long it = 0; it < (1L << 26); ++it) {
                int v = ldflag_l3(&flg[lane]);
                if (__ballot(v >= tgt) == ~0ull) break;
                __builtin_amdgcn_s_sleep(1);
            }
            __atomic_signal_fence(__ATOMIC_SEQ_CST);
            if (t > 0) {
                const _Float16* hb = h0s + ((t - 1) & 3) * (64 * 512)
                                   + arow * 512 + q * 8;
                half8 ah[16];
                #pragma unroll
                for (int u = 0; u < 16; ++u) ah[u] = ldfrag_l3(hb + u * 32);
                #pragma unroll
                for (int u = 0; u < 16; ++u) {
                    if (u & 1) acc1 = MFMA(ah[u], bw[16 + u], acc1);
                    else       acc0 = MFMA(ah[u], bw[16 + u], acc0);
                }
            }
        } else {
            const int tgt = (lf == 0) ? (t + 1) : t;
            for (long it = 0; it < (1L << 26); ++it) {
                int v = ldflag_l3(&flg[lane]);
                if (__ballot(v >= tgt) == ~0ull) break;
                __builtin_amdgcn_s_sleep(1);
            }
            __atomic_signal_fence(__ATOMIC_SEQ_CST);
            {
                const _Float16* xa = h0s + (t & 3) * (64 * 512) + arow * 512 + q * 8;
                half8 ax[16];
                #pragma unroll
                for (int u = 0; u < 16; ++u) ax[u] = ldfrag_l3(xa + u * 32);
                #pragma unroll
                for (int u = 0; u < 16; ++u) {
                    if (u & 1) acc1 = MFMA(ax[u], bw[u], acc1);
                    else       acc0 = MFMA(ax[u], bw[u], acc0);
                }
            }
            if (t > 0) {
                const _Float16* hb = h1s + ((t - 1) & 3) * (64 * 512)
                                   + arow * 512 + q * 8;
                half8 ah[16];
                #pragma unroll
                for (int u = 0; u < 16; ++u) ah[u] = ldfrag_l3(hb + u * 32);
                #pragma unroll
                for (int u = 0; u < 16; ++u) {
                    if (u & 1) acc1 = MFMA(ah[u], bw[16 + u], acc1);
                    else       acc0 = MFMA(ah[u], bw[16 + u], acc0);
                }
            }
        }

        float hv[4];
        #pragma unroll
        for (int r = 0; r < 4; ++r)
            hv[r] = tanhf(acc0[r] + acc1[r] + bias);

        if (t == SEQ - 1) {
            #pragma unroll
            for (int r = 0; r < 4; ++r)
                out[(size_t)L * 64 * 512 + (size_t)(bg * 16 + q * 4 + r) * 512 + col]
                    = hv[r];
        }
        {
            _Float16* hw = ((L == 0) ? h0s : h1s) + (t & 3) * (64 * 512)
                         + (size_t)(bg * 16) * 512 + col;
            #pragma unroll
            for (int r = 0; r < 4; ++r) {
                union { _Float16 f; unsigned short u; } cv;
                cv.f = (_Float16)hv[r];
                st2_l3(hw + (q * 4 + r) * 512, cv.u);
            }
        }
        __atomic_signal_fence(__ATOMIC_SEQ_CST);
        __builtin_amdgcn_s_waitcnt(0);
        __atomic_signal_fence(__ATOMIC_SEQ_CST);
        if (lane == 0)
            stflag_l3(&flg[L * 32 + jg], t + 1);
    }
}

// ===== fast path: block stamps + LDS-coalesced stores =====
__device__ __forceinline__ void run_fast(
    const int t0, const int tid, const int lane, const int w,
    const int L, const int g, const int qb, const int jg,
    const int* __restrict__ src, const float* __restrict__ embed,
    const half8* bw, const float bias, float* __restrict__ out,
    _Float16* h0f, _Float16* h1f, int* stamps, _Float16* lds)
{
    const int q    = lane >> 4;
    const int rr   = lane & 15;
    const int col  = jg * 16 + rr;
    const int arow = g * 16 + rr;
    const int lcol = w * 16 + rr;        // col within block's 128-col slab
    const int srow = tid >> 5;           // coalesced-store row 0..15
    const int sseg = tid & 31;           // 8-B segment within row
    int* myst = stamps + (L * 4 + qb) * FSTR;
    int degraded = 0;

    for (int t = t0; t < SEQ; ++t) {
        floatx4 acc0 = {0.f,0.f,0.f,0.f}, acc1 = {0.f,0.f,0.f,0.f};

        if (L == 0) {
            const int erow = src[arow * SEQ + t];
            const float* eb = embed + (size_t)erow * 512 + q * 8;
            half8 ax[16];
            #pragma unroll
            for (int u = 0; u < 16; ++u) ax[u] = cvt8(eb + u * 32);
            #pragma unroll
            for (int u = 0; u < 16; ++u) {
                if (u & 1) acc1 = MFMA(ax[u], bw[u], acc1);
                else       acc0 = MFMA(ax[u], bw[u], acc0);
            }
        }
        const int tA = (L == 0) ? t : (t + 1);        // L0-quarter target
        const int tB = (L == 0) ? (t - DMASK) : t;    // L1-quarter target

        {   // 4+4 block-stamp rendezvous, ballot-MIN
            const long bound = degraded ? 64 : (1L << 13);
            bool ok = false;
            for (long it = 0; it < bound; ++it) {
                int v = 0;
                if (lane < 8) v = ldstamp(stamps + lane * FSTR);
                const bool pass = (lane >= 8) || (v >= ((lane < 4) ? tA : tB));
                if (__ballot(pass) == ~0ull) { ok = true; break; }
                __builtin_amdgcn_s_sleep(1);
            }
            if (!ok) degraded = 1;
        }
        __atomic_signal_fence(__ATOMIC_SEQ_CST);

        if (L == 0) {
            if (t > 0) {
                const _Float16* hb = h0f + (size_t)((t - 1) & DMASK) * (64 * 512)
                                   + arow * 512 + q * 8;
                half8 ah[16];
                #pragma unroll
                for (int u = 0; u < 16; ++u) ah[u] = ldfrag_fast(hb + u * 32);
                #pragma unroll
                for (int u = 0; u < 16; ++u) {
                    if (u & 1) acc1 = MFMA(ah[u], bw[16 + u], acc1);
                    else       acc0 = MFMA(ah[u], bw[16 + u], acc0);
                }
            }
        } else {
            {
                const _Float16* xa = h0f + (size_t)(t & DMASK) * (64 * 512)
                                   + arow * 512 + q * 8;
                half8 ax[16];
                #pragma unroll
                for (int u = 0; u < 16; ++u) ax[u] = ldfrag_fast(xa + u * 32);
                #pragma unroll
                for (int u = 0; u < 16; ++u) {
                    if (u & 1) acc1 = MFMA(ax[u], bw[u], acc1);
                    else       acc0 = MFMA(ax[u], bw[u], acc0);
                }
            }
            if (t > 0) {
                const _Float16* hb = h1f + (size_t)((t - 1) & DMASK) * (64 * 512)
                                   + arow * 512 + q * 8;
                half8 ah[16];
                #pragma unroll
                for (int u = 0; u < 16; ++u) ah[u] = ldfrag_fast(hb + u * 32);
                #pragma unroll
                for (int u = 0; u < 16; ++u) {
                    if (u & 1) acc1 = MFMA(ah[u], bw[16 + u], acc1);
                    else       acc0 = MFMA(ah[u], bw[16 + u], acc0);
                }
            }
        }

        float hv[4];
        #pragma unroll
        for (int r = 0; r < 4; ++r)
            hv[r] = tanhf(acc0[r] + acc1[r] + bias);

        if (t == SEQ - 1) {
            #pragma unroll
            for (int r = 0; r < 4; ++r)
                out[(size_t)L * 64 * 512 + (size_t)(g * 16 + q * 4 + r) * 512 + col]
                    = hv[r];
        }

        // ---- h store: C/D frags -> LDS transpose -> 64 x 8B stores ----
        #pragma unroll
        for (int r = 0; r < 4; ++r)
            lds[(q * 4 + r) * 128 + lcol] = (_Float16)hv[r];
        __syncthreads();                              // lgkm drained
        {
            u64 v = *reinterpret_cast<const u64*>(&lds[srow * 128 + sseg * 4]);
            _Float16* dst = ((L == 0) ? h0f : h1f)
                          + (size_t)(t & DMASK) * (64 * 512)
                          + (size_t)(g * 16 + srow) * 512 + qb * 128 + sseg * 4;
            *reinterpret_cast<u64*>(dst) = v;         // plain write-through
        }
        __syncthreads();        // implicit vmcnt(0): ALL waves' stores at L2
        if (tid == 0) ststamp(myst, t + 1);
    }
}

// ===== probe: steps 0..PROBE-1 on slow truth, mirroring + validating =====
__device__ __forceinline__ void run_probe(
    const int tid, const int lane, const int w,
    const int L, const int g, const int qb, const int jg,
    const int* __restrict__ src, const float* __restrict__ embed,
    const half8* bw, const float bias,
    _Float16* h0s, _Float16* h1s, int* flg,       // slow (truth), 4 slots
    _Float16* f0s, _Float16* f1s, int* stamps,    // fast mirrors
    _Float16* lds, int* verdict)
{
    const int q    = lane >> 4;
    const int rr   = lane & 15;
    const int col  = jg * 16 + rr;
    const int arow = g * 16 + rr;
    const int lcol = w * 16 + rr;
    const int srow = tid >> 5;
    const int sseg = tid & 31;
    const int lf   = lane >> 5;
    int* mystF = stamps + (L * 4 + qb) * FSTR;
    int bad = 0;

    for (int t = 0; t < PROBE; ++t) {
        floatx4 acc0 = {0.f,0.f,0.f,0.f}, acc1 = {0.f,0.f,0.f,0.f};
        const int tgt = (L == 0) ? ((lf == 0) ? t : (t - 3))
                                 : ((lf == 0) ? (t + 1) : t);

        if (L == 0) {
            const int erow = src[arow * SEQ + t];
            const float* eb = embed + (size_t)erow * 512 + q * 8;
            half8 ax[16];
            #pragma unroll
            for (int u = 0; u < 16; ++u) ax[u] = cvt8(eb + u * 32);
            #pragma unroll
            for (int u = 0; u < 16; ++u) {
                if (u & 1) acc1 = MFMA(ax[u], bw[u], acc1);
                else       acc0 = MFMA(ax[u], bw[u], acc0);
            }
        }

        // slow poll (ground-truth rendezvous)
        for (long it = 0; it < (1L << 26); ++it) {
            int v = ldflag_l3(&flg[lane]);
            if (__ballot(v >= tgt) == ~0ull) break;
            __builtin_amdgcn_s_sleep(1);
        }
        __atomic_signal_fence(__ATOMIC_SEQ_CST);

        // fast block-stamp check (bounded; timeout = defect, not hang)
        {
            const int tA = (L == 0) ? t : (t + 1);
            const int tB = (L == 0) ? (t - DMASK) : t;
            bool ok = false;
            for (long it = 0; it < 256; ++it) {
                int v = 0;
                if (lane < 8) v = ldstamp(stamps + lane * FSTR);
                const bool pass = (lane >= 8) || (v >= ((lane < 4) ? tA : tB));
                if (__ballot(pass) == ~0ull) { ok = true; break; }
                __builtin_amdgcn_s_sleep(1);
            }
            if (!ok) bad = 1;
        }

        if (L == 0) {
            if (t > 0) {
                const size_t offS = ((t - 1) & 3) * (64 * 512) + arow * 512 + q * 8;
                const size_t offF = (size_t)((t - 1) & DMASK) * (64 * 512)
                                  + arow * 512 + q * 8;
                half8 ah[16];
                #pragma unroll
                for (int u = 0; u < 16; ++u) {
                    ah[u] = ldfrag_l3(h0s + offS + u * 32);
                    half8 fh = ldfrag_fast(f0s + offF + u * 32);
                    bad |= neq8(ah[u], fh);
                }
                #pragma unroll
                for (int u = 0; u < 16; ++u) {
                    if (u & 1) acc1 = MFMA(ah[u], bw[16 + u], acc1);
                    else       acc0 = MFMA(ah[u], bw[16 + u], acc0);
                }
            }
        } else {
            {
                const size_t offS = (t & 3) * (64 * 512) + arow * 512 + q * 8;
                const size_t offF = (size_t)(t & DMASK) * (64 * 512)
                                  + arow * 512 + q * 8;
                half8 ax[16];
                #pragma unroll
                for (int u = 0; u < 16; ++u) {
                    ax[u] = ldfrag_l3(h0s + offS + u * 32);
                    half8 fh = ldfrag_fast(f0s + offF + u * 32);
                    bad |= neq8(ax[u], fh);
                }
                #pragma unroll
                for (int u = 0; u < 16; ++u) {
                    if (u & 1) acc1 = MFMA(ax[u], bw[u], acc1);
                    else       acc0 = MFMA(ax[u], bw[u], acc0);
                }
            }
            if (t > 0) {
                const size_t offS = ((t - 1) & 3) * (64 * 512) + arow * 512 + q * 8;
                const size_t offF = (size_t)((t - 1) & DMASK) * (64 * 512)
                                  + arow * 512 + q * 8;
                half8 ah[16];
                #pragma unroll
                for (int u = 0; u < 16; ++u) {
                    ah[u] = ldfrag_l3(h1s + offS + u * 32);
                    half8 fh = ldfrag_fast(f1s + offF + u * 32);
                    bad |= neq8(ah[u], fh);
                }
                #pragma unroll
                for (int u = 0; u < 16; ++u) {
                    if (u & 1) acc1 = MFMA(ah[u], bw[16 + u], acc1);
                    else       acc0 = MFMA(ah[u], bw[16 + u], acc0);
                }
            }
        }

        float hv[4];
        #pragma unroll
        for (int r = 0; r < 4; ++r)
            hv[r] = tanhf(acc0[r] + acc1[r] + bias);

        // slow stores (direct, agent) + fast stores (LDS transpose path)
        {
            const size_t offS = (t & 3) * (64 * 512) + (size_t)(g * 16) * 512 + col;
            _Float16* hwS = ((L == 0) ? h0s : h1s) + offS;
            #pragma unroll
            for (int r = 0; r < 4; ++r) {
                union { _Float16 f; unsigned short u; } cv;
                cv.f = (_Float16)hv[r];
                st2_l3(hwS + (q * 4 + r) * 512, cv.u);
                lds[(q * 4 + r) * 128 + lcol] = cv.f;
            }
        }
        __syncthreads();
        {
            u64 v = *reinterpret_cast<const u64*>(&lds[srow * 128 + sseg * 4]);
            _Float16* dst = ((L == 0) ? f0s : f1s)
                          + (size_t)(t & DMASK) * (64 * 512)
                          + (size_t)(g * 16 + srow) * 512 + qb * 128 + sseg * 4;
            *reinterpret_cast<u64*>(dst) = v;
        }
        if (t == PROBE - 1) {
            const int anybad = (__ballot(bad) != 0ull) ? 1 : 0;
            if (lane == 0 && anybad)
                __hip_atomic_fetch_or(verdict, 1, __ATOMIC_RELAXED,
                                      __HIP_MEMORY_SCOPE_AGENT);
        }
        __syncthreads();        // implicit vmcnt(0): slow+fast+verdict drained
        if (tid == 0) ststamp(mystF, t + 1);
        if (lane == 0) stflag_l3(&flg[L * 32 + jg], t + 1);
    }
}

__global__ __launch_bounds__(512, 1)
void rnn_persist(const int* __restrict__ src, const float* __restrict__ embed,
                 const float* __restrict__ W_ih, const float* __restrict__ W_hh,
                 const float* __restrict__ b_ih, const float* __restrict__ b_hh,
                 float* __restrict__ out, _Float16* hS, _Float16* hF,
                 int* flagsS, int* flagsF, int* verdict, int fastEnable)
{
    __shared__ _Float16 lds[16 * 128];   // 4 KB transpose tile
    const int b = blockIdx.x;
    if ((b & 7) >= 4) return;            // residues 4..7: padding blocks, exit
    const int g   = b & 7;               // group 0..3 = XCD under round-robin
    const int j   = b >> 3;              // 0..7
    const int L   = j & 1;               // layer
    const int qb  = j >> 1;              // col quarter 0..3
    const int tid = threadIdx.x;
    const int lane = tid & 63;
    const int w    = tid >> 6;           // wave in block 0..7
    const int jg   = qb * 8 + w;         // 16-col group 0..31

    // persistent weights: 16 cols x K=1024, f16, 128 VGPRs
    const int q = lane >> 4, rr = lane & 15;
    const int col = jg * 16 + rr;
    half8 bw[32];
    {
        const float* Wi = W_ih + ((size_t)L * 512 + col) * 512;
        const float* Wh = W_hh + ((size_t)L * 512 + col) * 512;
        #pragma unroll
        for (int u = 0; u < 16; ++u) bw[u]      = cvt8(Wi + u * 32 + q * 8);
        #pragma unroll
        for (int u = 0; u < 16; ++u) bw[16 + u] = cvt8(Wh + u * 32 + q * 8);
    }
    const float bias = b_ih[L * 512 + col] + b_hh[L * 512 + col];

    _Float16* h0sS = hS;  _Float16* h1sS = hS + 4 * 64 * 512;
    _Float16* h0sF = hF;  _Float16* h1sF = hF + (size_t)DEPTH * 64 * 512;
    int* flgS   = flagsS + g * 64;
    int* stamps = flagsF + g * 8 * FSTR;   // 8 spread block-stamps per group

    if (!fastEnable) {   // workspace too small: proven slow path only
        run_slow(0, lane, L, g, jg, src, embed, bw, bias, out,
                 h0sS, h1sS, flgS);
        return;
    }

    run_probe(tid, lane, w, L, g, qb, jg, src, embed, bw, bias,
              h0sS, h1sS, flgS, h0sF, h1sF, stamps, lds, &verdict[g]);

    // group barrier: all 64 stamps >= PROBE  =>  all verdict ORs are at MALL
    for (long it = 0; it < (1L << 26); ++it) {
        int v = ldflag_l3(&flgS[lane]);
        if (__ballot(v >= PROBE) == ~0ull) break;
        __builtin_amdgcn_s_sleep(1);
    }
    __atomic_signal_fence(__ATOMIC_SEQ_CST);
    const int vd = __hip_atomic_load(&verdict[g], __ATOMIC_RELAXED,
                                     __HIP_MEMORY_SCOPE_AGENT);

    if (vd == 0) {
        run_fast(PROBE, tid, lane, w, L, g, qb, jg, src, embed, bw, bias, out,
                 h0sF, h1sF, stamps, lds);
    } else {
        // telemetry stall ~2 ms: a slow verdict is readable from dur_us
        for (int i = 0; i < 600; ++i) __builtin_amdgcn_s_sleep(125);
        run_slow(PROBE, lane, L, g, jg, src, embed, bw, bias, out,
                 h0sS, h1sS, flgS);
    }
}

extern "C" void kernel_launch(void* const* d_in, const int* in_sizes, int n_in,
                              void* d_out, int out_size, void* d_ws, size_t ws_size,
                              hipStream_t stream) {
    const int*   src   = (const int*)  d_in[0];
    const float* embed = (const float*)d_in[1];
    const float* W_ih  = (const float*)d_in[2];
    const float* W_hh  = (const float*)d_in[3];
    const float* b_ih  = (const float*)d_in[4];
    const float* b_hh  = (const float*)d_in[5];
    float* out = (float*)d_out;

    int*      flagsS  = (int*)d_ws;                      // bytes [0,1024)
    int*      verdict = (int*)d_ws + 512;                // bytes [2048,2064)
    int*      flagsF  = (int*)((char*)d_ws + 32768);     // [32KB,..) spread
    _Float16* hS = (_Float16*)((char*)d_ws + 65536);     // 512 KB slow h
    // fast h: 2 layers x DEPTH(64) slots x 64x512 f16 = 8 MB at offset 1 MB
    const size_t need = (size_t)1048576
                      + (size_t)2 * DEPTH * 64 * 512 * 2 + 65536;
    const int fastEnable = (ws_size >= need) ? 1 : 0;
    _Float16* hF = fastEnable ? (_Float16*)((char*)d_ws + 1048576) : hS;

    // flags/verdict/stamps must start at 0 each launch (ws re-poisoned);
    // h slots need no init: t==0 skips all h-slot reads.
    hipMemsetAsync(d_ws, 0, 65536, stream);

    // 64 blocks x 512 threads; residues 0..3 (mod 8) active so each group's
    // 16 blocks (2 layers x 4 quarters) share one XCD; 1 block/CU by VGPR
    // capacity (136 <= 256), 8 blocks/XCD on 32 CUs.
    rnn_persist<<<dim3(64), dim3(512), 0, stream>>>(
        src, embed, W_ih, W_hh, b_ih, b_hh, out, hS, hF,
        flagsS, flagsF, verdict, fastEnable);
}

// Round 8
// 18806.523 us; speedup vs baseline: 2.1373x; 2.1373x over previous
//
#include <hip/hip_runtime.h>

// 2-layer tanh RNN, B=64, S=2048, D=HID=512.
// Round 15: back to the r7 skeleton (session-best 15.18 ms, agent-scope
// flag protocol, PROVEN) with two critical-path cuts; sync untouched.
//   1. Embed gather software-pipelined through LDS: step t+1's 32 KB embed
//      slice is staged with 32x16B global_load_lds (no VGPR round-trip)
//      issued right after step t's x-MFMAs; latency hides under the poll +
//      h-part + store (~4 us of cover). Consume = ds_read_b128 + cvt
//      (~0.5 us) instead of a ~2.5-3 us register-limited L3 gather chain.
//   2. h store coalesced: intra-wave LDS transpose (reusing the consumed
//      staging buffer half) -> 16x32B agent stores instead of 256x2B, so
//      the pre-stamp vmcnt(0) drain is shorter.
// Geometry: grid 256 x 64 threads (1 wave/block, 1 block/CU); tile
// (L=g>>7, bg=(g>>5)&3, jg=g&31) = 16 rows x 16 cols, K=1024 in VGPRs.
// r14 post-mortem: hierarchical stamps + barriers = 39 ms (worse); TCC-RMW
// polls lose to plain agent loads; convoy-width theory falsified. The
// remaining chain is embed-gather + L3 hops; this round removes the gather.

#define SEQ 2048

typedef _Float16 half8 __attribute__((ext_vector_type(8)));
typedef float floatx4 __attribute__((ext_vector_type(4)));
typedef unsigned long long u64;

__device__ inline half8 cvt8(const float* p) {
    float4 f0 = ((const float4*)p)[0];
    float4 f1 = ((const float4*)p)[1];
    half8 h;
    h[0]=(_Float16)f0.x; h[1]=(_Float16)f0.y; h[2]=(_Float16)f0.z; h[3]=(_Float16)f0.w;
    h[4]=(_Float16)f1.x; h[5]=(_Float16)f1.y; h[6]=(_Float16)f1.z; h[7]=(_Float16)f1.w;
    return h;
}

__device__ inline u64 ld8(const void* p) {
    return __hip_atomic_load((const u64*)p, __ATOMIC_RELAXED, __HIP_MEMORY_SCOPE_AGENT);
}
__device__ inline half8 ldfrag(const _Float16* p) {   // 16 B coherent load
    union { u64 d[2]; half8 h; } u;
    u.d[0] = ld8(p);
    u.d[1] = ld8(p + 4);
    return u.h;
}

// async global->LDS copy, 16 B per lane; LDS dest = uniform base + lane*16
__device__ inline void glds16(const float* g, const float* l) {
    __builtin_amdgcn_global_load_lds(
        (const __attribute__((address_space(1))) void*)g,
        (__attribute__((address_space(3))) void*)l, 16, 0, 0);
}

#define MFMA(a, b, c) __builtin_amdgcn_mfma_f32_16x16x32_f16((a), (b), (c), 0, 0, 0)

__global__ __launch_bounds__(64, 1)
void rnn_persist(const int* __restrict__ src, const float* __restrict__ embed,
                 const float* __restrict__ W_ih, const float* __restrict__ W_hh,
                 const float* __restrict__ b_ih, const float* __restrict__ b_hh,
                 float* __restrict__ out, _Float16* hbase, int* flags)
{
    // staging: [buf][u][half][lane][4 floats] = 64 KB exactly.
    __shared__ float ebuf[2][16][2][64][4];

    const int lane = threadIdx.x;
    const int g    = blockIdx.x;         // tile id 0..255
    const int L    = g >> 7;
    const int bg   = (g >> 5) & 3;
    const int jg   = g & 31;
    const int q    = lane >> 4;
    const int rr   = lane & 15;
    const int col  = jg * 16 + rr;

    _Float16* h0s = hbase;                         // 4 slots of 64x512 f16
    _Float16* h1s = hbase + 4 * 64 * 512;          // 4 slots of 64x512 f16

    // ---- persistent weights: 16 cols x K=1024, f16, 128 VGPRs ----
    half8 bw[32];
    {
        const float* Wi = W_ih + ((size_t)L * 512 + col) * 512;
        const float* Wh = W_hh + ((size_t)L * 512 + col) * 512;
        #pragma unroll
        for (int u = 0; u < 16; ++u) bw[u]      = cvt8(Wi + u * 32 + q * 8);
        #pragma unroll
        for (int u = 0; u < 16; ++u) bw[16 + u] = cvt8(Wh + u * 32 + q * 8);
    }
    const float bias = b_ih[L * 512 + col] + b_hh[L * 512 + col];

    const int arow = bg * 16 + rr;       // batch row whose A-frags this lane loads
    int* flg = flags + bg * 64;          // [layer(2)][jg(32)] stamps for this bg
    const int lf = lane >> 5;            // which layer's flag this lane polls

    // ---- prologue: stage embed for t=0 ----
    if (L == 0) {
        const int e0 = src[arow * SEQ];
        const float* eb = embed + (size_t)e0 * 512 + q * 8;
        #pragma unroll
        for (int u = 0; u < 16; ++u) {
            glds16(eb + u * 32,     &ebuf[0][u][0][0][0]);
            glds16(eb + u * 32 + 4, &ebuf[0][u][1][0][0]);
        }
    }

    for (int t = 0; t < SEQ; ++t) {
        floatx4 acc0 = {0.f,0.f,0.f,0.f}, acc1 = {0.f,0.f,0.f,0.f};
        const int cur = t & 1;

        if (L == 0) {
            // ---- x-part from staged LDS (loads issued last step) ----
            asm volatile("s_waitcnt vmcnt(0)" ::: "memory");
            __builtin_amdgcn_sched_barrier(0);
            #pragma unroll
            for (int u = 0; u < 16; ++u) {
                float4 f0 = *reinterpret_cast<const float4*>(&ebuf[cur][u][0][lane][0]);
                float4 f1 = *reinterpret_cast<const float4*>(&ebuf[cur][u][1][lane][0]);
                half8 a;
                a[0]=(_Float16)f0.x; a[1]=(_Float16)f0.y; a[2]=(_Float16)f0.z; a[3]=(_Float16)f0.w;
                a[4]=(_Float16)f1.x; a[5]=(_Float16)f1.y; a[6]=(_Float16)f1.z; a[7]=(_Float16)f1.w;
                if (u & 1) acc1 = MFMA(a, bw[u], acc1);
                else       acc0 = MFMA(a, bw[u], acc0);
            }
            // ---- stage embed for t+1 (fire-and-forget, no VGPRs) ----
            if (t + 1 < SEQ) {
                const int en = src[arow * SEQ + t + 1];
                const float* eb = embed + (size_t)en * 512 + q * 8;
                #pragma unroll
                for (int u = 0; u < 16; ++u) {
                    glds16(eb + u * 32,     &ebuf[cur ^ 1][u][0][0][0]);
                    glds16(eb + u * 32 + 4, &ebuf[cur ^ 1][u][1][0][0]);
                }
            }
            // ---- wait: h0 peers done step t-1; layer-1 past t-4 (WAR) ----
            const int tgt = (lf == 0) ? t : (t - 3);
            for (long it = 0; it < (1L << 26); ++it) {
                int v = __hip_atomic_load(&flg[lane], __ATOMIC_RELAXED,
                                          __HIP_MEMORY_SCOPE_AGENT);
                if (__ballot(v >= tgt) == ~0ull) break;
                __builtin_amdgcn_s_sleep(1);
            }
            __atomic_signal_fence(__ATOMIC_SEQ_CST);
            // ---- h-part: h0_{t-1} ----
            if (t > 0) {
                const _Float16* hb = h0s + ((t - 1) & 3) * (64 * 512)
                                   + arow * 512 + q * 8;
                half8 ah[16];
                #pragma unroll
                for (int u = 0; u < 16; ++u) ah[u] = ldfrag(hb + u * 32);
                #pragma unroll
                for (int u = 0; u < 16; ++u) {
                    if (u & 1) acc1 = MFMA(ah[u], bw[16 + u], acc1);
                    else       acc0 = MFMA(ah[u], bw[16 + u], acc0);
                }
            }
        } else {
            // ---- wait: h0_t ready (stamp_0 >= t+1); h1 peers done t-1 ----
            const int tgt = (lf == 0) ? (t + 1) : t;
            for (long it = 0; it < (1L << 26); ++it) {
                int v = __hip_atomic_load(&flg[lane], __ATOMIC_RELAXED,
                                          __HIP_MEMORY_SCOPE_AGENT);
                if (__ballot(v >= tgt) == ~0ull) break;
                __builtin_amdgcn_s_sleep(1);
            }
            __atomic_signal_fence(__ATOMIC_SEQ_CST);
            // ---- x-part: h0_t ----
            {
                const _Float16* xa = h0s + (t & 3) * (64 * 512)
                                   + arow * 512 + q * 8;
                half8 ax[16];
                #pragma unroll
                for (int u = 0; u < 16; ++u) ax[u] = ldfrag(xa + u * 32);
                #pragma unroll
                for (int u = 0; u < 16; ++u) {
                    if (u & 1) acc1 = MFMA(ax[u], bw[u], acc1);
                    else       acc0 = MFMA(ax[u], bw[u], acc0);
                }
            }
            // ---- h-part: h1_{t-1} ----
            if (t > 0) {
                const _Float16* hb = h1s + ((t - 1) & 3) * (64 * 512)
                                   + arow * 512 + q * 8;
                half8 ah[16];
                #pragma unroll
                for (int u = 0; u < 16; ++u) ah[u] = ldfrag(hb + u * 32);
                #pragma unroll
                for (int u = 0; u < 16; ++u) {
                    if (u & 1) acc1 = MFMA(ah[u], bw[16 + u], acc1);
                    else       acc0 = MFMA(ah[u], bw[16 + u], acc0);
                }
            }
        }

        // ---- finalize: bias + tanh; C/D layout row=q*4+r, col=rr ----
        float hv[4];
        #pragma unroll
        for (int r = 0; r < 4; ++r)
            hv[r] = tanhf(acc0[r] + acc1[r] + bias);

        if (t == SEQ - 1) {
            #pragma unroll
            for (int r = 0; r < 4; ++r)
                out[(size_t)L * 64 * 512 + (size_t)(bg * 16 + q * 4 + r) * 512 + col]
                    = hv[r];
        }

        // ---- h store: intra-wave LDS transpose -> 16x32B agent stores ----
        // Scratch aliases the CONSUMED staging half (L0: buf cur; L1: buf 0).
        // Next global write to that region is t+1's prefetch (after this read).
        {
            _Float16* hb2 = (_Float16*)&ebuf[(L == 0) ? cur : 0][0][0][0][0];
            #pragma unroll
            for (int r = 0; r < 4; ++r)
                hb2[(q * 4 + r) * 16 + rr] = (_Float16)hv[r];
            asm volatile("s_waitcnt lgkmcnt(0)" ::: "memory");
            __builtin_amdgcn_sched_barrier(0);
            const int lrow = lane >> 2, seg = lane & 3;
            u64 v = *reinterpret_cast<const u64*>(&hb2[lrow * 16 + seg * 4]);
            _Float16* dst = ((L == 0) ? h0s : h1s) + (t & 3) * (64 * 512)
                          + (size_t)(bg * 16 + lrow) * 512 + jg * 16 + seg * 4;
            __hip_atomic_store((u64*)dst, v, __ATOMIC_RELAXED,
                               __HIP_MEMORY_SCOPE_AGENT);
        }
        __atomic_signal_fence(__ATOMIC_SEQ_CST);
        __builtin_amdgcn_s_waitcnt(0);      // whole wave's h stores at L3
        __atomic_signal_fence(__ATOMIC_SEQ_CST);
        if (lane == 0)
            __hip_atomic_store(&flg[L * 32 + jg], t + 1, __ATOMIC_RELAXED,
                               __HIP_MEMORY_SCOPE_AGENT);
    }
}

extern "C" void kernel_launch(void* const* d_in, const int* in_sizes, int n_in,
                              void* d_out, int out_size, void* d_ws, size_t ws_size,
                              hipStream_t stream) {
    const int*   src   = (const int*)  d_in[0];
    const float* embed = (const float*)d_in[1];
    const float* W_ih  = (const float*)d_in[2];
    const float* W_hh  = (const float*)d_in[3];
    const float* b_ih  = (const float*)d_in[4];
    const float* b_hh  = (const float*)d_in[5];
    float*     out   = (float*)d_out;
    int*       flags = (int*)d_ws;                            // [4 bg][2][32]
    _Float16*  hbase = (_Float16*)((char*)d_ws + 16384);      // 8 slots 64x512

    // flags must start at 0 (ws re-poisoned to 0xAA each timed launch);
    // h slots need no init: t==0 skips all h-slot reads.
    hipMemsetAsync(d_ws, 0, 16384, stream);

    // Plain launch: 256 blocks x 64 threads (1 wave each), co-residency by
    // capacity (grid = 256 = #CUs, 1 block/CU by __launch_bounds__).
    rnn_persist<<<dim3(256), dim3(64), 0, stream>>>(
        src, embed, W_ih, W_hh, b_ih, b_hh, out, hbase, flags);
}